// Round 9
// baseline (86.663 us; speedup 1.0000x reference)
//
#include <hip/hip_runtime.h>
#include <hip/hip_bf16.h>

// Problem geometry (fixed by the reference)
#define BD   4
#define SD   8
#define LSEC 256
#define LL   254
#define DD   768
#define MAXS 100
#define TT   (SD*LL)   // 2032
#define NC4  (TT/4)    // 508 f4 per mask row

// Flat output offsets (float32 elements, reference return order)
#define OFF_SF  0LL                       // sentence_feature [4,100,768]
#define OFF_TM  307200LL                  // tran_mask        [4,2032,8]
#define OFF_TMS 372224LL                  // tran_mask_sec    [4,100,8]
#define OFF_SMF 375424LL                  // sentence_mask_full [4,2032,2032]
#define OFF_SEC (375424LL + 16516096LL)   // section_mask_full  [4,2032,2032]
#define OFF_LOG 33407616LL                // logits1 [4,2]

#define NROWS  (BD*TT)                    // 8128 rows per mask
#define NUNITS (NROWS*2)                  // 16256 fill units (SMF then SEC)
#define UPB    8                          // rows per fill block
#define USPLIT (NROWS + 1280)             // K0 fills units [0,USPLIT)
#define NFILL0 (USPLIT/UPB)               // 1176
#define NFILL1 ((NUNITS - USPLIT)/UPB)    // 856

// K0 partition: pool, prep, fill0
#define NPOOL (BD*MAXS*3)                 // 1200
#define NPREP BD
// K1 partition: gemm, window, fill1
#define NGEMM 300                         // 25 row-tiles x 12 col-tiles (16x64)
#define NWIN  (BD*SD*16)                  // 512 (16 rows each)

typedef float f4 __attribute__((ext_vector_type(4)));

// Zero UPB row-units (unit: one 2032-float row of one mask), skipping the
// 64-f4 diagonal window of each row. Nontemporal f4 stores.
__device__ __forceinline__ void fill_units(float* __restrict__ out, int unit0, int tid) {
    const f4 z4 = {0.f, 0.f, 0.f, 0.f};
    #pragma unroll
    for (int q = 0; q < UPB; ++q) {
        int u = unit0 + q;
        long long base = (u < NROWS) ? OFF_SMF : OFF_SEC;
        int row  = (u < NROWS) ? u : u - NROWS;   // 0..8127 == b*TT + t1
        int t1   = row % TT;
        int j1   = t1 / LL;
        int wlo4 = (j1*LL) >> 2;
        f4* rp = (f4*)(out + base + (long long)row * TT);
        #pragma unroll
        for (int h = 0; h < 2; ++h) {
            int c4i = tid + h*256;
            if (c4i < NC4 && (unsigned)(c4i - wlo4) >= 64u)
                __builtin_nontemporal_store(z4, &rp[c4i]);
        }
    }
}

// ---------------------------------------------------------------------------
// K0: pool + prep + fill0 (SMF + 1280 SEC rows)
// ---------------------------------------------------------------------------
union K0S {
    struct { int ids[TT]; int cnt[SD]; int st[SD]; float red[256]; } p;
    struct { int sf, sl; } q;
};

__global__ __launch_bounds__(256) void k0_kernel(
    const float* __restrict__ atf,     // [32][256][768]
    const float* __restrict__ pf,      // pooled_feature [32][768]
    const int*   __restrict__ ids_g,   // [B][T], nondecreasing runs 1..100
    const float* __restrict__ Wcls,    // [2][768]
    const float* __restrict__ bcls,    // [2]
    float* __restrict__ pooled,        // [400][768] ws
    float* __restrict__ out)
{
    __shared__ K0S sm;
    const int blk = blockIdx.x;
    const int tid = threadIdx.x;

    if (blk < NPOOL) {
        // ---------- pool: (sentence, d-chunk) max over contiguous range ----
        const int sent = blk % (BD*MAXS);
        const int d0   = (blk / (BD*MAXS)) << 8;   // 0,256,512
        const int b    = sent / MAXS;
        const int sid  = sent % MAXS + 1;

        if (tid == 0) { sm.q.sf = TT; sm.q.sl = -1; }
        __syncthreads();
        int lf = TT, lm = -1;
        for (int t = tid; t < TT; t += 256) {
            if (ids_g[b*TT + t] == sid) { lf = min(lf, t); lm = max(lm, t); }
        }
        atomicMin(&sm.q.sf, lf);
        atomicMax(&sm.q.sl, lm);
        __syncthreads();
        const int f = sm.q.sf, l = sm.q.sl;

        float m = 0.0f;                    // absent sentence id -> zero
        if (l >= 0) {
            float mm[8];
            #pragma unroll
            for (int q = 0; q < 8; ++q) mm[q] = -INFINITY;
            for (int t = f; t <= l; t += 8) {
                #pragma unroll
                for (int q = 0; q < 8; ++q) {
                    int tq = min(t + q, l);
                    long long r = ((long long)(b*SD + tq / LL) * LSEC + 1 + tq % LL) * DD + d0 + tid;
                    mm[q] = fmaxf(mm[q], atf[r]);
                }
            }
            #pragma unroll
            for (int q = 4; q > 0; q >>= 1)
                #pragma unroll
                for (int u = 0; u < q; ++u) mm[u] = fmaxf(mm[u], mm[u+q]);
            m = mm[0];
        }
        pooled[(long long)sent * DD + d0 + tid] = m;
        return;
    }

    if (blk < NPOOL + NPREP) {
        // -------- prep: tran_mask_sec + tran_mask + logits1 for doc b ------
        const int b = blk - NPOOL;
        for (int t = tid; t < TT; t += 256) sm.p.ids[t] = ids_g[b*TT + t];
        if (tid < SD) sm.p.cnt[tid] = 0;
        __syncthreads();
        for (int t = tid; t < TT; t += 256) {
            int j = t / LL;
            bool bnd = (t % LL == 0) || (sm.p.ids[t] != sm.p.ids[t-1]);
            if (bnd) atomicAdd(&sm.p.cnt[j], 1);
        }
        __syncthreads();
        if (tid == 0) {
            int acc = 0;
            for (int j = 0; j < SD; ++j) { sm.p.st[j] = acc; acc += sm.p.cnt[j]; }
        }
        __syncthreads();
        for (int idx = tid; idx < MAXS*SD; idx += 256) {
            int r = idx / SD, j = idx % SD;
            float v = (r >= sm.p.st[j] && r < sm.p.st[j] + sm.p.cnt[j]) ? 1.0f : 0.0f;
            out[OFF_TMS + (long long)b*(MAXS*SD) + idx] = v;
        }
        for (int idx = tid; idx < TT*2; idx += 256) {
            int row = idx >> 1, h = idx & 1;
            int j1 = row / LL;
            f4 v;
            v.x = (4*h + 0 == j1) ? 1.f : 0.f;
            v.y = (4*h + 1 == j1) ? 1.f : 0.f;
            v.z = (4*h + 2 == j1) ? 1.f : 0.f;
            v.w = (4*h + 3 == j1) ? 1.f : 0.f;
            __builtin_nontemporal_store(v, (f4*)(out + OFF_TM + ((long long)b*TT + row)*SD + 4*h));
        }
        float acc0 = 0.f, acc1 = 0.f;
        #pragma unroll
        for (int k = 0; k < 3; ++k) {
            int d = tid + k*256;
            float mv = pf[(b*SD)*DD + d];
            #pragma unroll
            for (int j = 1; j < SD; ++j) mv = fmaxf(mv, pf[(b*SD + j)*DD + d]);
            acc0 += mv * Wcls[d];
            acc1 += mv * Wcls[DD + d];
        }
        sm.p.red[tid] = acc0; __syncthreads();
        for (int off = 128; off > 0; off >>= 1) { if (tid < off) sm.p.red[tid] += sm.p.red[tid+off]; __syncthreads(); }
        float l0 = sm.p.red[0];
        __syncthreads();
        sm.p.red[tid] = acc1; __syncthreads();
        for (int off = 128; off > 0; off >>= 1) { if (tid < off) sm.p.red[tid] += sm.p.red[tid+off]; __syncthreads(); }
        if (tid == 0) {
            out[OFF_LOG + b*2 + 0] = l0          + bcls[0];
            out[OFF_LOG + b*2 + 1] = sm.p.red[0] + bcls[1];
        }
        return;
    }

    // ---------- fill0 ------------------------------------------------------
    fill_units(out, (blk - NPOOL - NPREP) * UPB, tid);
}

// ---------------------------------------------------------------------------
// K1: gemm (first, hides under fill) + window + fill1 (rest of SEC)
// ---------------------------------------------------------------------------
union K1S {
    struct { float As[16][68]; float Ws[64][64]; } g;                  // 20736 B
    struct { int sid[256]; float sam[256]; } w;
};

__global__ __launch_bounds__(256) void k1_kernel(
    const int*   __restrict__ att,     // [32][256]
    const int*   __restrict__ ids_g,   // [B][T]
    const float* __restrict__ Wg2,     // [768][768] row-major [e][d]
    const float* __restrict__ pooled,  // [400][768] ws
    float* __restrict__ out)
{
    __shared__ K1S sm;
    const int blk = blockIdx.x;
    const int tid = threadIdx.x;

    if (blk < NGEMM) {
        // -------- gemm: out_sf[r][e] = sum_d pooled[r][d]*Wg2[e][d] --------
        const int r0 = (blk % 25) * 16;
        const int e0 = (blk / 25) * 64;
        const int aI  = tid >> 4;          // A row 0..15
        const int aC4 = (tid & 15) * 4;    // col group
        const int k4  = tid & 15;
        const int er = tid & 63;           // output col within tile
        const int sr = tid >> 6;           // wave id 0..3 -> rows 4sr..4sr+3
        float acc[4] = {0.f, 0.f, 0.f, 0.f};

        f4 aR = *(const f4*)&pooled[(long long)(r0 + aI)*DD + aC4];
        f4 wR[4];
        #pragma unroll
        for (int it = 0; it < 4; ++it)
            wR[it] = *(const f4*)&Wg2[(long long)(e0 + aI + 16*it)*DD + aC4];

        for (int kt = 0; kt < 12; ++kt) {
            *(f4*)&sm.g.As[aI][aC4] = aR;
            #pragma unroll
            for (int it = 0; it < 4; ++it) {
                int row = aI + 16*it;
                *(f4*)&sm.g.Ws[row][((k4 ^ (row & 15)) << 2)] = wR[it];
            }
            __syncthreads();
            if (kt + 1 < 12) {
                int kb = (kt + 1) * 64;
                aR = *(const f4*)&pooled[(long long)(r0 + aI)*DD + kb + aC4];
                #pragma unroll
                for (int it = 0; it < 4; ++it)
                    wR[it] = *(const f4*)&Wg2[(long long)(e0 + aI + 16*it)*DD + kb + aC4];
            }
            #pragma unroll
            for (int k4r = 0; k4r < 16; ++k4r) {
                f4 w = *(f4*)&sm.g.Ws[er][((k4r ^ (er & 15)) << 2)];
                #pragma unroll
                for (int rr = 0; rr < 4; ++rr) {
                    f4 a = *(f4*)&sm.g.As[4*sr + rr][k4r*4];   // wave-uniform
                    acc[rr] += a.x*w.x + a.y*w.y + a.z*w.z + a.w*w.w;
                }
            }
            __syncthreads();
        }
        #pragma unroll
        for (int rr = 0; rr < 4; ++rr)
            out[OFF_SF + (long long)(r0 + 4*sr + rr)*DD + e0 + er] = acc[rr];
        return;
    }

    if (blk < NGEMM + NWIN) {
        // -------- window: write the 64-f4 diagonal window of 16 rows -------
        const int idx0  = blk - NGEMM;       // 0..511
        const int sec   = idx0 >> 4;         // 0..31
        const int chunk = idx0 & 15;         // 16 rows each
        const int b  = sec >> 3;
        const int j1 = sec & 7;
        const int cstart  = j1 * LL;
        const int wlo4    = cstart >> 2;
        const int sh      = cstart & 3;      // 0 or 2
        {
            int k = tid;
            int i2 = k - sh;
            bool v = (i2 >= 0) & (i2 < LL);
            sm.w.sid[k] = v ? ids_g[b*TT + cstart + i2] : -1;
            sm.w.sam[k] = v ? (float)att[(b*SD + j1)*LSEC + 1 + i2] : 0.f;
        }
        __syncthreads();
        #pragma unroll
        for (int it = 0; it < 4; ++it) {
            int idx = tid + it*256;          // 16 rows x 64 u
            int rr = idx >> 6, u = idx & 63;
            int i1 = chunk*16 + rr;
            if (i1 >= LL) continue;
            const int   myid = sm.w.sid[i1 + sh];
            const float am1  = sm.w.sam[i1 + sh];
            int4 s4 = *(int4*)&sm.w.sid[u*4];
            f4   a4 = *(f4*)  &sm.w.sam[u*4];
            f4 v4, v5;
            v4.x = (s4.x == myid) ? 1.f : 0.f;
            v4.y = (s4.y == myid) ? 1.f : 0.f;
            v4.z = (s4.z == myid) ? 1.f : 0.f;
            v4.w = (s4.w == myid) ? 1.f : 0.f;
            v5 = a4 * am1;
            float* row4 = out + OFF_SMF + ((long long)b*TT + cstart + i1) * TT + (wlo4 + u)*4;
            __builtin_nontemporal_store(v4, (f4*)row4);
            __builtin_nontemporal_store(v5, (f4*)(row4 + (OFF_SEC - OFF_SMF)));
        }
        return;
    }

    // ---------- fill1 ------------------------------------------------------
    fill_units(out, USPLIT + (blk - NGEMM - NWIN) * UPB, tid);
}

// ---------------------------------------------------------------------------
extern "C" void kernel_launch(void* const* d_in, const int* in_sizes, int n_in,
                              void* d_out, int out_size, void* d_ws, size_t ws_size,
                              hipStream_t stream)
{
    const float* atf  = (const float*)d_in[0];  // all_token_feature [32,256,768]
    const float* pf   = (const float*)d_in[1];  // pooled_feature    [32,768]
    const int*   att  = (const int*)  d_in[2];  // attention_mask    [32,256]
    const int*   ids  = (const int*)  d_in[3];  // sentence_mask     [4,8,254]
    const float* Wg2  = (const float*)d_in[4];  // W_g2 [768,768]
    const float* Wcls = (const float*)d_in[5];  // W_cls [2,768]
    const float* bcls = (const float*)d_in[6];  // b_cls [2]
    float* out = (float*)d_out;

    float* pooled = (float*)d_ws;               // [400][768] = 1.23 MB

    hipLaunchKernelGGL(k0_kernel, dim3(NPOOL + NPREP + NFILL0), dim3(256), 0, stream,
                       atf, pf, ids, Wcls, bcls, pooled, out);
    hipLaunchKernelGGL(k1_kernel, dim3(NGEMM + NWIN + NFILL1), dim3(256), 0, stream,
                       att, ids, Wg2, pooled, out);
}

// Round 10
// 58.629 us; speedup vs baseline: 1.4781x; 1.4781x over previous
//
#include <hip/hip_runtime.h>
#include <hip/hip_bf16.h>

// Problem geometry (fixed by the reference)
#define BD   4
#define SD   8
#define LSEC 256
#define LL   254
#define DD   768
#define MAXS 100
#define TT   (SD*LL)   // 2032
#define NC4  (TT/4)    // 508 f4 per mask row

// Flat output offsets (float32 elements, reference return order)
#define OFF_SF  0LL                       // sentence_feature [4,100,768]
#define OFF_TM  307200LL                  // tran_mask        [4,2032,8]
#define OFF_TMS 372224LL                  // tran_mask_sec    [4,100,8]
#define OFF_SMF 375424LL                  // sentence_mask_full [4,2032,2032]
#define OFF_SEC (375424LL + 16516096LL)   // section_mask_full  [4,2032,2032]
#define OFF_LOG 33407616LL                // logits1 [4,2]

#define NROWS (BD*TT)                     // 8128 rows per mask
#define UPB   8                           // rows per fill block
#define NFILL (NROWS/UPB)                 // 1016 fill blocks per mask

// K0 partition: window, pool, prep, SMF-fill
#define NWIN  (BD*SD*16)                  // 512 (16 rows each)
#define NPOOL (BD*MAXS*3)                 // 1200
#define NPREP BD
// K1 partition: gemm first, then SEC-fill
#define NGEMM 300                         // 25 row-tiles x 12 col-tiles (16x64)

typedef float f4 __attribute__((ext_vector_type(4)));

// Zero UPB rows of ONE mask, skipping the 64-f4 diagonal window of each row.
// Plain f4 stores (L2 write-back path — 2.3 TB/s on d_out; nt stores are 1.5x slower).
__device__ __forceinline__ void fill_rows(float* __restrict__ out, long long maskoff,
                                          int row0, int tid) {
    const f4 z4 = {0.f, 0.f, 0.f, 0.f};
    #pragma unroll
    for (int q = 0; q < UPB; ++q) {
        int row = row0 + q;               // 0..8127 == b*TT + t1
        int t1  = row % TT;
        int j1  = t1 / LL;
        int wlo4 = (j1*LL) >> 2;
        f4* rp = (f4*)(out + maskoff + (long long)row * TT);
        #pragma unroll
        for (int h = 0; h < 2; ++h) {
            int c4i = tid + h*256;
            if (c4i >= NC4) continue;
            if ((unsigned)(c4i - wlo4) < 64u) continue;   // window: window blocks write it
            rp[c4i] = z4;
        }
    }
}

// ---------------------------------------------------------------------------
// K0: window + pool + prep + SMF fill
// ---------------------------------------------------------------------------
union K0S {
    struct { int ids[TT]; int cnt[SD]; int st[SD]; float red[256]; } p;
    struct { int sf, sl; } q;
    struct { int sid[256]; float sam[256]; } w;
};

__global__ __launch_bounds__(256) void k0_kernel(
    const float* __restrict__ atf,     // [32][256][768]
    const float* __restrict__ pf,      // pooled_feature [32][768]
    const int*   __restrict__ att,     // [32][256]
    const int*   __restrict__ ids_g,   // [B][T], nondecreasing runs 1..100
    const float* __restrict__ Wcls,    // [2][768]
    const float* __restrict__ bcls,    // [2]
    float* __restrict__ pooled,        // [400][768] ws
    float* __restrict__ out)
{
    __shared__ K0S sm;
    const int blk = blockIdx.x;
    const int tid = threadIdx.x;

    if (blk < NWIN) {
        // -------- window: write the 64-f4 diagonal window of 16 rows -------
        const int sec   = blk >> 4;          // 0..31
        const int chunk = blk & 15;          // 16 rows each
        const int b  = sec >> 3;
        const int j1 = sec & 7;
        const int cstart  = j1 * LL;
        const int wlo4    = cstart >> 2;
        const int sh      = cstart & 3;      // 0 or 2
        {
            int k = tid;
            int i2 = k - sh;
            bool v = (i2 >= 0) & (i2 < LL);
            sm.w.sid[k] = v ? ids_g[b*TT + cstart + i2] : -1;
            sm.w.sam[k] = v ? (float)att[(b*SD + j1)*LSEC + 1 + i2] : 0.f;
        }
        __syncthreads();
        #pragma unroll
        for (int it = 0; it < 4; ++it) {
            int idx = tid + it*256;          // 16 rows x 64 u
            int rr = idx >> 6, u = idx & 63;
            int i1 = chunk*16 + rr;
            if (i1 >= LL) continue;
            const int   myid = sm.w.sid[i1 + sh];
            const float am1  = sm.w.sam[i1 + sh];
            int4 s4 = *(int4*)&sm.w.sid[u*4];
            f4   a4 = *(f4*)  &sm.w.sam[u*4];
            f4 v4, v5;
            v4.x = (s4.x == myid) ? 1.f : 0.f;
            v4.y = (s4.y == myid) ? 1.f : 0.f;
            v4.z = (s4.z == myid) ? 1.f : 0.f;
            v4.w = (s4.w == myid) ? 1.f : 0.f;
            v5 = a4 * am1;
            float* row4 = out + OFF_SMF + ((long long)b*TT + cstart + i1) * TT + (wlo4 + u)*4;
            *(f4*)row4 = v4;
            *(f4*)(row4 + (OFF_SEC - OFF_SMF)) = v5;
        }
        return;
    }

    if (blk < NWIN + NPOOL) {
        // ---------- pool: (sentence, d-chunk) max over contiguous range ----
        const int p    = blk - NWIN;
        const int sent = p % (BD*MAXS);
        const int d0   = (p / (BD*MAXS)) << 8;   // 0,256,512
        const int b    = sent / MAXS;
        const int sid  = sent % MAXS + 1;

        if (tid == 0) { sm.q.sf = TT; sm.q.sl = -1; }
        __syncthreads();
        int lf = TT, lm = -1;
        for (int t = tid; t < TT; t += 256) {
            if (ids_g[b*TT + t] == sid) { lf = min(lf, t); lm = max(lm, t); }
        }
        atomicMin(&sm.q.sf, lf);
        atomicMax(&sm.q.sl, lm);
        __syncthreads();
        const int f = sm.q.sf, l = sm.q.sl;

        float m = 0.0f;                    // absent sentence id -> zero
        if (l >= 0) {
            float mm[8];
            #pragma unroll
            for (int q = 0; q < 8; ++q) mm[q] = -INFINITY;
            for (int t = f; t <= l; t += 8) {
                #pragma unroll
                for (int q = 0; q < 8; ++q) {
                    int tq = min(t + q, l);
                    long long r = ((long long)(b*SD + tq / LL) * LSEC + 1 + tq % LL) * DD + d0 + tid;
                    mm[q] = fmaxf(mm[q], atf[r]);
                }
            }
            #pragma unroll
            for (int q = 4; q > 0; q >>= 1)
                #pragma unroll
                for (int u = 0; u < q; ++u) mm[u] = fmaxf(mm[u], mm[u+q]);
            m = mm[0];
        }
        pooled[(long long)sent * DD + d0 + tid] = m;
        return;
    }

    if (blk < NWIN + NPOOL + NPREP) {
        // -------- prep: tran_mask_sec + tran_mask + logits1 for doc b ------
        const int b = blk - NWIN - NPOOL;
        for (int t = tid; t < TT; t += 256) sm.p.ids[t] = ids_g[b*TT + t];
        if (tid < SD) sm.p.cnt[tid] = 0;
        __syncthreads();
        for (int t = tid; t < TT; t += 256) {
            int j = t / LL;
            bool bnd = (t % LL == 0) || (sm.p.ids[t] != sm.p.ids[t-1]);
            if (bnd) atomicAdd(&sm.p.cnt[j], 1);
        }
        __syncthreads();
        if (tid == 0) {
            int acc = 0;
            for (int j = 0; j < SD; ++j) { sm.p.st[j] = acc; acc += sm.p.cnt[j]; }
        }
        __syncthreads();
        for (int idx = tid; idx < MAXS*SD; idx += 256) {
            int r = idx / SD, j = idx % SD;
            float v = (r >= sm.p.st[j] && r < sm.p.st[j] + sm.p.cnt[j]) ? 1.0f : 0.0f;
            out[OFF_TMS + (long long)b*(MAXS*SD) + idx] = v;
        }
        for (int idx = tid; idx < TT*2; idx += 256) {
            int row = idx >> 1, h = idx & 1;
            int j1 = row / LL;
            f4 v;
            v.x = (4*h + 0 == j1) ? 1.f : 0.f;
            v.y = (4*h + 1 == j1) ? 1.f : 0.f;
            v.z = (4*h + 2 == j1) ? 1.f : 0.f;
            v.w = (4*h + 3 == j1) ? 1.f : 0.f;
            *(f4*)(out + OFF_TM + ((long long)b*TT + row)*SD + 4*h) = v;
        }
        float acc0 = 0.f, acc1 = 0.f;
        #pragma unroll
        for (int k = 0; k < 3; ++k) {
            int d = tid + k*256;
            float mv = pf[(b*SD)*DD + d];
            #pragma unroll
            for (int j = 1; j < SD; ++j) mv = fmaxf(mv, pf[(b*SD + j)*DD + d]);
            acc0 += mv * Wcls[d];
            acc1 += mv * Wcls[DD + d];
        }
        sm.p.red[tid] = acc0; __syncthreads();
        for (int off = 128; off > 0; off >>= 1) { if (tid < off) sm.p.red[tid] += sm.p.red[tid+off]; __syncthreads(); }
        float l0 = sm.p.red[0];
        __syncthreads();
        sm.p.red[tid] = acc1; __syncthreads();
        for (int off = 128; off > 0; off >>= 1) { if (tid < off) sm.p.red[tid] += sm.p.red[tid+off]; __syncthreads(); }
        if (tid == 0) {
            out[OFF_LOG + b*2 + 0] = l0          + bcls[0];
            out[OFF_LOG + b*2 + 1] = sm.p.red[0] + bcls[1];
        }
        return;
    }

    // ---------- SMF fill ---------------------------------------------------
    fill_rows(out, OFF_SMF, (blk - NWIN - NPOOL - NPREP) * UPB, tid);
}

// ---------------------------------------------------------------------------
// K1: gemm (first, hides under fill) + SEC fill
// ---------------------------------------------------------------------------
__global__ __launch_bounds__(256) void k1_kernel(
    const float* __restrict__ Wg2,     // [768][768] row-major [e][d]
    const float* __restrict__ pooled,  // [400][768] ws
    float* __restrict__ out)
{
    __shared__ __align__(16) float As[16][68];
    __shared__ __align__(16) float Ws[64][64];
    const int blk = blockIdx.x;
    const int tid = threadIdx.x;

    if (blk >= NGEMM) {
        fill_rows(out, OFF_SEC, (blk - NGEMM) * UPB, tid);
        return;
    }

    // -------- gemm: out_sf[r][e] = sum_d pooled[r][d]*Wg2[e][d] ------------
    const int r0 = (blk % 25) * 16;
    const int e0 = (blk / 25) * 64;
    const int aI  = tid >> 4;          // A row 0..15
    const int aC4 = (tid & 15) * 4;    // col group
    const int k4  = tid & 15;
    const int er = tid & 63;           // output col within tile
    const int sr = tid >> 6;           // wave id 0..3 -> rows 4sr..4sr+3
    float acc[4] = {0.f, 0.f, 0.f, 0.f};

    f4 aR = *(const f4*)&pooled[(long long)(r0 + aI)*DD + aC4];
    f4 wR[4];
    #pragma unroll
    for (int it = 0; it < 4; ++it)
        wR[it] = *(const f4*)&Wg2[(long long)(e0 + aI + 16*it)*DD + aC4];

    for (int kt = 0; kt < 12; ++kt) {
        *(f4*)&As[aI][aC4] = aR;
        #pragma unroll
        for (int it = 0; it < 4; ++it) {
            int row = aI + 16*it;
            *(f4*)&Ws[row][((k4 ^ (row & 15)) << 2)] = wR[it];
        }
        __syncthreads();
        if (kt + 1 < 12) {
            int kb = (kt + 1) * 64;
            aR = *(const f4*)&pooled[(long long)(r0 + aI)*DD + kb + aC4];
            #pragma unroll
            for (int it = 0; it < 4; ++it)
                wR[it] = *(const f4*)&Wg2[(long long)(e0 + aI + 16*it)*DD + kb + aC4];
        }
        #pragma unroll
        for (int k4r = 0; k4r < 16; ++k4r) {
            f4 w = *(f4*)&Ws[er][((k4r ^ (er & 15)) << 2)];
            #pragma unroll
            for (int rr = 0; rr < 4; ++rr) {
                f4 a = *(f4*)&As[4*sr + rr][k4r*4];   // wave-uniform
                acc[rr] += a.x*w.x + a.y*w.y + a.z*w.z + a.w*w.w;
            }
        }
        __syncthreads();
    }
    #pragma unroll
    for (int rr = 0; rr < 4; ++rr)
        out[OFF_SF + (long long)(r0 + 4*sr + rr)*DD + e0 + er] = acc[rr];
}

// ---------------------------------------------------------------------------
extern "C" void kernel_launch(void* const* d_in, const int* in_sizes, int n_in,
                              void* d_out, int out_size, void* d_ws, size_t ws_size,
                              hipStream_t stream)
{
    const float* atf  = (const float*)d_in[0];  // all_token_feature [32,256,768]
    const float* pf   = (const float*)d_in[1];  // pooled_feature    [32,768]
    const int*   att  = (const int*)  d_in[2];  // attention_mask    [32,256]
    const int*   ids  = (const int*)  d_in[3];  // sentence_mask     [4,8,254]
    const float* Wg2  = (const float*)d_in[4];  // W_g2 [768,768]
    const float* Wcls = (const float*)d_in[5];  // W_cls [2,768]
    const float* bcls = (const float*)d_in[6];  // b_cls [2]
    float* out = (float*)d_out;

    float* pooled = (float*)d_ws;               // [400][768] = 1.23 MB

    hipLaunchKernelGGL(k0_kernel, dim3(NWIN + NPOOL + NPREP + NFILL), dim3(256), 0, stream,
                       atf, pf, att, ids, Wcls, bcls, pooled, out);
    hipLaunchKernelGGL(k1_kernel, dim3(NGEMM + NFILL), dim3(256), 0, stream,
                       Wg2, pooled, out);
}